// Round 1
// 385.864 us; speedup vs baseline: 1.0369x; 1.0369x over previous
//
#include <hip/hip_runtime.h>
#include <hip/hip_bf16.h>

#define B 4
#define H 480
#define W 640
#define HW (H*W)
#define BHW (B*H*W)
#define NKP 1024
#define THRESH 0.005f
#define CAP 16384
#define NCOL (B*NKP)
#define KTOT 704
#define KPB 4

typedef __attribute__((ext_vector_type(8))) short s8v;
typedef __attribute__((ext_vector_type(4))) float f4v;

__device__ __forceinline__ short f2bf(float f) {
    __hip_bfloat16 h = __float2bfloat16(f);
    return *(short*)&h;
}

// ================= fused weights + bias + counter zero (Mw now bf16) =================
__global__ void fuse_all(const float* __restrict__ merge_w, const float* __restrict__ merge_b,
                         const float* __restrict__ lin0_w, const float* __restrict__ lin0_b,
                         const float* __restrict__ lin1_w, const float* __restrict__ lin1_b,
                         const float* __restrict__ lin2_w, const float* __restrict__ lin2_b,
                         short* __restrict__ Mw, float* __restrict__ biasf, int* __restrict__ cnt) {
    if (blockIdx.x == 704) {
        int o = threadIdx.x;
        if (o < 4) cnt[o * 64] = 0;
        float acc = merge_b[o];
        for (int k = 0; k < 64; ++k)  acc += merge_w[o * KTOT + k] * lin2_b[k];
        for (int k = 0; k < 128; ++k) acc += merge_w[o * KTOT + 64 + k] * lin1_b[k];
        for (int k = 0; k < 256; ++k) acc += merge_w[o * KTOT + 448 + k] * lin0_b[k];
        biasf[o] = acc;
        return;
    }
    int e = blockIdx.x * 256 + threadIdx.x;
    int o = e / KTOT;
    int j = e - o * KTOT;
    float acc = 0.0f;
    if (j < 64) {
        for (int k = 0; k < 64; ++k) acc += merge_w[o * KTOT + k] * lin2_w[k * 64 + j];
    } else if (j < 192) {
        int jj = j - 64;
        for (int k = 0; k < 128; ++k) acc += merge_w[o * KTOT + 64 + k] * lin1_w[k * 128 + jj];
    } else if (j < 448) {
        acc = merge_w[o * KTOT + j];
    } else {
        int jj = j - 448;
        for (int k = 0; k < 256; ++k) acc += merge_w[o * KTOT + 448 + k] * lin0_w[k * 256 + jj];
    }
    Mw[o * KTOT + j] = f2bf(acc);
}

// ================= NMS stage 1: mask0 = (S == pool9(S)) =================
__global__ __launch_bounds__(256) void nms1(const float* __restrict__ scores,
                                            float* __restrict__ mask) {
    __shared__ float tile[40][40];
    __shared__ float hm[40][32];
    int bz = blockIdx.z;
    int x0 = blockIdx.x * 32, y0 = blockIdx.y * 32;
    const float* sp = scores + bz * HW;
    for (int t = threadIdx.x; t < 1600; t += 256) {
        int ly = t / 40, lx = t - ly * 40;
        int gy = y0 - 4 + ly, gx = x0 - 4 + lx;
        tile[ly][lx] = (gy >= 0 && gy < H && gx >= 0 && gx < W) ? sp[gy * W + gx] : -INFINITY;
    }
    __syncthreads();
    for (int t = threadIdx.x; t < 1280; t += 256) {
        int ly = t >> 5, lx = t & 31;
        float m = tile[ly][lx];
        #pragma unroll
        for (int d = 1; d < 9; ++d) m = fmaxf(m, tile[ly][lx + d]);
        hm[ly][lx] = m;
    }
    __syncthreads();
    for (int t = threadIdx.x; t < 1024; t += 256) {
        int ly = t >> 5, lx = t & 31;
        float m = hm[ly][lx];
        #pragma unroll
        for (int d = 1; d < 9; ++d) m = fmaxf(m, hm[ly + d][lx]);
        float s = tile[ly + 4][lx + 4];
        mask[bz * HW + (y0 + ly) * W + x0 + lx] = (s == m) ? 1.0f : 0.0f;
    }
}

// ===== NMS stage 2: remaining 4 pools (2 NMS iterations) fused in LDS + compaction =====
__global__ __launch_bounds__(256) void nms2_compact(const float* __restrict__ scores,
                                                    const float* __restrict__ mask0,
                                                    unsigned long long* __restrict__ cand,
                                                    int* __restrict__ cnt) {
    __shared__ float Sm[56 * 56];   // S on local [4,60)
    __shared__ float Mm[64 * 64];   // mask on local [0,64)
    __shared__ float Zm[56 * 56];   // Z on local [4,60)
    __shared__ float Tm[64 * 56];   // h-pass temp
    __shared__ int lcnt, gbase;
    int bz = blockIdx.z;
    int x0 = blockIdx.x * 32, y0 = blockIdx.y * 32;
    const float* sp = scores + bz * HW;
    const float* mp = mask0 + bz * HW;
    if (threadIdx.x == 0) lcnt = 0;
    for (int t = threadIdx.x; t < 4096; t += 256) {
        int ly = t >> 6, lx = t & 63;
        int gy = y0 - 16 + ly, gx = x0 - 16 + lx;
        Mm[t] = (gy >= 0 && gy < H && gx >= 0 && gx < W) ? mp[gy * W + gx] : 0.0f;
    }
    for (int t = threadIdx.x; t < 3136; t += 256) {
        int i = t / 56, j = t - i * 56;
        int gy = y0 - 12 + i, gx = x0 - 12 + j;
        Sm[t] = (gy >= 0 && gy < H && gx >= 0 && gx < W) ? sp[gy * W + gx] : -1.0f;
    }
    __syncthreads();
    for (int t = threadIdx.x; t < 3584; t += 256) {
        int i = t / 56, c = t - i * 56;
        float m = Mm[i * 64 + c];
        #pragma unroll
        for (int d = 1; d < 9; ++d) m = fmaxf(m, Mm[i * 64 + c + d]);
        Tm[i * 56 + c] = m;
    }
    __syncthreads();
    for (int t = threadIdx.x; t < 3136; t += 256) {
        int i = t / 56, c = t - i * 56;
        float m = Tm[i * 56 + c];
        #pragma unroll
        for (int d = 1; d < 9; ++d) m = fmaxf(m, Tm[(i + d) * 56 + c]);
        Zm[t] = (m > 0.0f) ? -1.0f : Sm[t];
    }
    __syncthreads();
    for (int t = threadIdx.x; t < 2688; t += 256) {
        int i = t / 48, c = t - i * 48;
        float m = Zm[i * 56 + c];
        #pragma unroll
        for (int d = 1; d < 9; ++d) m = fmaxf(m, Zm[i * 56 + c + d]);
        Tm[i * 56 + c] = m;
    }
    __syncthreads();
    for (int t = threadIdx.x; t < 2304; t += 256) {
        int r = t / 48, c = t - r * 48;
        float m = Tm[r * 56 + c];
        #pragma unroll
        for (int d = 1; d < 9; ++d) m = fmaxf(m, Tm[(r + d) * 56 + c]);
        float Zc = Zm[(r + 4) * 56 + c + 4];
        int mi = (r + 8) * 64 + c + 8;
        bool nm = (Zc == m) && (Zc >= 0.0f);
        Mm[mi] = (Mm[mi] != 0.0f || nm) ? 1.0f : 0.0f;
    }
    __syncthreads();
    for (int t = threadIdx.x; t < 1920; t += 256) {
        int r = t / 40, c = t - r * 40;
        float m = Mm[(r + 8) * 64 + c + 8];
        #pragma unroll
        for (int d = 1; d < 9; ++d) m = fmaxf(m, Mm[(r + 8) * 64 + c + 8 + d]);
        Tm[r * 56 + c] = m;
    }
    __syncthreads();
    for (int t = threadIdx.x; t < 1600; t += 256) {
        int r = t / 40, c = t - r * 40;
        float m = Tm[r * 56 + c];
        #pragma unroll
        for (int d = 1; d < 9; ++d) m = fmaxf(m, Tm[(r + d) * 56 + c]);
        int zi = (r + 8) * 56 + c + 8;
        Zm[zi] = (m > 0.0f) ? -1.0f : Sm[zi];
    }
    __syncthreads();
    for (int t = threadIdx.x; t < 1280; t += 256) {
        int r = t / 32, c = t & 31;
        float m = Zm[(r + 8) * 56 + c + 8];
        #pragma unroll
        for (int d = 1; d < 9; ++d) m = fmaxf(m, Zm[(r + 8) * 56 + c + 8 + d]);
        Tm[r * 56 + c] = m;
    }
    __syncthreads();
    unsigned long long keys[4];
    int nl = 0;
    #pragma unroll
    for (int q = 0; q < 4; ++q) {
        int t = threadIdx.x + q * 256;
        int r3 = t >> 5, c = t & 31;
        float m = Tm[r3 * 56 + c];
        #pragma unroll
        for (int d = 1; d < 9; ++d) m = fmaxf(m, Tm[(r3 + d) * 56 + c]);
        float Zc = Zm[(r3 + 12) * 56 + c + 12];
        bool fin = (Mm[(r3 + 16) * 64 + c + 16] != 0.0f) || ((Zc == m) && (Zc >= 0.0f));
        int gy = y0 + r3, gx = x0 + c;
        float sc = Sm[(r3 + 12) * 56 + c + 12];
        if (fin && gy >= 4 && gy < H - 4 && gx >= 4 && gx < W - 4 && sc > THRESH) {
            unsigned r = (unsigned)(gy * W + gx);
            unsigned bits = __float_as_uint(sc) | 0x80000000u;
            keys[nl++] = ((unsigned long long)bits << 32) |
                         (unsigned long long)(0xFFFFFFFFu - r);
        }
    }
    int lpos = 0;
    if (nl) lpos = atomicAdd(&lcnt, nl);
    __syncthreads();
    if (threadIdx.x == 0) gbase = (lcnt > 0) ? atomicAdd(&cnt[bz * 64], lcnt) : 0;
    __syncthreads();
    for (int j = 0; j < nl; ++j) {
        int p = gbase + lpos + j;
        if (p < CAP) cand[(size_t)bz * CAP + p] = keys[j];
    }
}

// ===== topk: TWO-LEVEL histogram select (22-bit prefix) + bitonic; emits spatial perm =====
__global__ __launch_bounds__(1024) void topk(const unsigned long long* __restrict__ cand,
                                             const int* __restrict__ cnt,
                                             float* __restrict__ out, int* __restrict__ fidx,
                                             int* __restrict__ perm) {
    __shared__ int hist[2048];
    __shared__ unsigned long long buf[4096];
    __shared__ int scnt, spiv1, spiv2, sabove;
    int b = blockIdx.x, tid = threadIdx.x;
    int m = cnt[b * 64]; if (m > CAP) m = CAP;
    const unsigned long long* cb = cand + (size_t)b * CAP;
    int target = (m < 1024) ? m : 1024;

    hist[tid] = 0; hist[tid + 1024] = 0;
    if (tid == 0) { scnt = 0; spiv1 = 2048; spiv2 = 0; sabove = 0; }
    __syncthreads();
    // pass 1: histogram of key bits [63:53]
    for (int i = tid; i < m; i += 1024)
        atomicAdd(&hist[(int)(cb[i] >> 53) & 0x7FF], 1);
    __syncthreads();
    for (int d = 1; d < 2048; d <<= 1) {
        int v0 = hist[tid] + ((tid + d < 2048) ? hist[tid + d] : 0);
        int v1 = hist[tid + 1024] + ((tid + 1024 + d < 2048) ? hist[tid + 1024 + d] : 0);
        __syncthreads();
        hist[tid] = v0; hist[tid + 1024] = v1;
        __syncthreads();
    }
    if (target > 0) {
        for (int t = tid; t < 2048; t += 1024) {
            int c = hist[t];
            int cn = (t < 2047) ? hist[t + 1] : 0;
            if (c >= target && cn < target) { spiv1 = t; sabove = cn; }
        }
    }
    __syncthreads();
    int piv1 = spiv1;
    int target2 = target - sabove;   // >= 1 when target > 0
    // pass 2: histogram of bits [52:42] within pivot bin
    hist[tid] = 0; hist[tid + 1024] = 0;
    __syncthreads();
    for (int i = tid; i < m; i += 1024) {
        unsigned long long k = cb[i];
        if (((int)(k >> 53) & 0x7FF) == piv1)
            atomicAdd(&hist[(int)(k >> 42) & 0x7FF], 1);
    }
    __syncthreads();
    for (int d = 1; d < 2048; d <<= 1) {
        int v0 = hist[tid] + ((tid + d < 2048) ? hist[tid + d] : 0);
        int v1 = hist[tid + 1024] + ((tid + 1024 + d < 2048) ? hist[tid + 1024 + d] : 0);
        __syncthreads();
        hist[tid] = v0; hist[tid + 1024] = v1;
        __syncthreads();
    }
    if (target > 0) {
        for (int t = tid; t < 2048; t += 1024) {
            int c = hist[t];
            int cn = (t < 2047) ? hist[t + 1] : 0;
            if (c >= target2 && cn < target2) spiv2 = t;
        }
    }
    __syncthreads();
    int piv2 = spiv2;
    // select: bin1 > piv1, or bin1 == piv1 && bin2 >= piv2  (~target + few keys)
    for (int i = tid; i < m; i += 1024) {
        unsigned long long k = cb[i];
        int b1 = (int)(k >> 53) & 0x7FF;
        bool sel = (target > 0) &&
                   (b1 > piv1 || (b1 == piv1 && (((int)(k >> 42) & 0x7FF) >= piv2)));
        if (sel) {
            int p = atomicAdd(&scnt, 1);
            if (p < 4096) buf[p] = k;
        }
    }
    __syncthreads();
    int sc_ = scnt; if (sc_ > 4096) sc_ = 4096;
    int ns = 1024; while (ns < sc_) ns <<= 1;
    for (int t = tid; t < ns; t += 1024) if (t >= sc_) buf[t] = 0ULL;
    __syncthreads();
    for (int k = 2; k <= ns; k <<= 1)
        for (int j = k >> 1; j > 0; j >>= 1) {
            __syncthreads();
            for (int t = tid; t < ns; t += 1024) {
                int ixj = t ^ j;
                if (ixj > t) {
                    unsigned long long a = buf[t], bb = buf[ixj];
                    if (((t & k) == 0) ? (a < bb) : (a > bb)) { buf[t] = bb; buf[ixj] = a; }
                }
            }
        }
    __syncthreads();
    unsigned long long key = buf[tid];
    float kx, ky, sc;
    unsigned idx;
    if (key != 0ULL) {
        unsigned ord = (unsigned)(key >> 32);
        sc = __uint_as_float(ord ^ 0x80000000u);
        idx = 0xFFFFFFFFu - (unsigned)(key & 0xFFFFFFFFu);
        kx = (float)(idx % W);
        ky = (float)(idx / W);
    } else {
        sc = -1.0f; idx = 0; kx = 0.0f; ky = 0.0f;
    }
    int bn = b * NKP + tid;
    out[bn * 2 + 0] = kx;
    out[bn * 2 + 1] = ky;
    out[B * NKP * 2 + bn] = sc;
    fidx[bn] = (int)idx;
    __syncthreads();
    // spatial sort: keys (pixel<<10)|n ascending -> processing perm
    unsigned* b32 = (unsigned*)buf;
    b32[tid] = (idx << 10) | (unsigned)tid;
    for (int k = 2; k <= 1024; k <<= 1)
        for (int j = k >> 1; j > 0; j >>= 1) {
            __syncthreads();
            int ixj = tid ^ j;
            if (ixj > tid) {
                unsigned a = b32[tid], bb = b32[ixj];
                if (((tid & k) == 0) ? (a > bb) : (a < bb)) { b32[tid] = bb; b32[ixj] = a; }
            }
        }
    __syncthreads();
    perm[b * NKP + tid] = (int)(b32[tid] & 1023u);
}

// ===== fused descriptor sampling; KPB keypoints per block for 4x MLP; bf16 X output =====
__global__ __launch_bounds__(704) void sample_all(const float* __restrict__ d1,
                                                  const float* __restrict__ d2,
                                                  const float* __restrict__ cDa,
                                                  const float* __restrict__ d4,
                                                  const int* __restrict__ fidx,
                                                  const int* __restrict__ perm,
                                                  short* __restrict__ X) {
    __shared__ float ssum[KPB][12];
    int c = threadIdx.x;
    int wid = c >> 6, lane = c & 63;
    int b = blockIdx.x >> 8;                 // 256 blocks per batch (1024 kp / KPB)
    int g0 = (blockIdx.x & 255) * KPB;

    const float* map; int h, w, s, C, cl;
    if (c < 64)       { map = d1;  h = 240; w = 320; s = 2;  cl = c;       C = 64; }
    else if (c < 192) { map = d2;  h = 120; w = 160; s = 4;  cl = c - 64;  C = 128; }
    else if (c < 448) { map = cDa; h = 60;  w = 80;  s = 8;  cl = c - 192; C = 256; }
    else              { map = d4;  h = 30;  w = 40;  s = 16; cl = c - 448; C = 256; }
    const float* plane = map + ((size_t)(b * C + cl)) * (h * w);

    int cols[KPB];
    float vals[KPB];
    float t00[KPB], t01[KPB], t10[KPB], t11[KPB];
    float w00[KPB], w01[KPB], w10[KPB], w11[KPB];

    #pragma unroll
    for (int k = 0; k < KPB; ++k) {
        int col = (b << 10) | perm[(b << 10) + g0 + k];
        cols[k] = col;
        int idx = fidx[col];
        float kx = (float)(idx % W);
        float ky = (float)(idx / W);
        float kxs = kx - (float)s * 0.5f + 0.5f;
        float kys = ky - (float)s * 0.5f + 0.5f;
        float gx = kxs / (float)(w * s - 1) * 2.0f - 1.0f;
        float gy = kys / (float)(h * s - 1) * 2.0f - 1.0f;
        float x = (gx + 1.0f) * 0.5f * (float)(w - 1);
        float y = (gy + 1.0f) * 0.5f * (float)(h - 1);
        float x0f = floorf(x), y0f = floorf(y);
        int x0 = (int)x0f, y0 = (int)y0f;
        float wx1 = x - x0f, wy1 = y - y0f;
        float wx0 = 1.0f - wx1, wy0 = 1.0f - wy1;
        bool vx0 = (x0 >= 0) && (x0 < w);
        bool vx1 = (x0 + 1 >= 0) && (x0 + 1 < w);
        bool vy0 = (y0 >= 0) && (y0 < h);
        bool vy1 = (y0 + 1 >= 0) && (y0 + 1 < h);
        int xc0 = min(max(x0, 0), w - 1), xc1 = min(max(x0 + 1, 0), w - 1);
        int yc0 = min(max(y0, 0), h - 1), yc1 = min(max(y0 + 1, 0), h - 1);
        w00[k] = (vx0 && vy0) ? wx0 * wy0 : 0.0f;
        w01[k] = (vx1 && vy0) ? wx1 * wy0 : 0.0f;
        w10[k] = (vx0 && vy1) ? wx0 * wy1 : 0.0f;
        w11[k] = (vx1 && vy1) ? wx1 * wy1 : 0.0f;
        t00[k] = plane[yc0 * w + xc0];
        t01[k] = plane[yc0 * w + xc1];
        t10[k] = plane[yc1 * w + xc0];
        t11[k] = plane[yc1 * w + xc1];
    }
    #pragma unroll
    for (int k = 0; k < KPB; ++k)
        vals[k] = t00[k] * w00[k] + t01[k] * w01[k] + t10[k] * w10[k] + t11[k] * w11[k];

    // per-wave reduction of squares (segments are wave-aligned: 1/2/4/4 waves)
    #pragma unroll
    for (int k = 0; k < KPB; ++k) {
        float r = vals[k] * vals[k];
        #pragma unroll
        for (int off = 32; off > 0; off >>= 1) r += __shfl_xor(r, off, 64);
        if (lane == 0) ssum[k][wid] = r;
    }
    __syncthreads();
    int wbeg, wcnt;
    if (c < 64)       { wbeg = 0; wcnt = 1; }
    else if (c < 192) { wbeg = 1; wcnt = 2; }
    else if (c < 448) { wbeg = 3; wcnt = 4; }
    else              { wbeg = 7; wcnt = 4; }
    #pragma unroll
    for (int k = 0; k < KPB; ++k) {
        float sum = 0.0f;
        for (int t = 0; t < wcnt; ++t) sum += ssum[k][wbeg + t];
        float denom = fmaxf(sqrtf(sum), 1e-12f);
        X[(size_t)cols[k] * KTOT + c] = f2bf(vals[k] / denom);
    }
}

// ===== GEMM (bf16 MFMA): out[256,4096] = Mw[256,704] * X^T + bias; bf16 inputs =====
__global__ __launch_bounds__(256) void gemm_mfma(const short* __restrict__ Mw,
                                                 const short* __restrict__ X,
                                                 const float* __restrict__ biasf,
                                                 float* __restrict__ out) {
    __shared__ short As[64 * 72];
    __shared__ short Bs[64 * 72];
    int tid = threadIdx.x;
    int lane = tid & 63, w = tid >> 6;
    int r = lane & 15, quad = lane >> 4;
    int rowBase = blockIdx.y * 64, colBase = blockIdx.x * 64;
    int sm = tid >> 2, skq = (tid & 3) << 4;   // 16 shorts (32B) per thread per tile

    const short* pa = Mw + (size_t)(rowBase + sm) * KTOT + skq;
    const short* pb = X + (size_t)(colBase + sm) * KTOT + skq;
    s8v a0 = *(const s8v*)(pa), a1 = *(const s8v*)(pa + 8);
    s8v b0 = *(const s8v*)(pb), b1 = *(const s8v*)(pb + 8);

    f4v acc[4];
    #pragma unroll
    for (int t = 0; t < 4; ++t) acc[t] = (f4v)0.0f;

    for (int kt = 0; kt < 11; ++kt) {
        __syncthreads();
        *(s8v*)&As[sm * 72 + skq + 0] = a0;
        *(s8v*)&As[sm * 72 + skq + 8] = a1;
        *(s8v*)&Bs[sm * 72 + skq + 0] = b0;
        *(s8v*)&Bs[sm * 72 + skq + 8] = b1;
        __syncthreads();
        if (kt < 10) {
            pa += 64; pb += 64;
            a0 = *(const s8v*)(pa); a1 = *(const s8v*)(pa + 8);
            b0 = *(const s8v*)(pb); b1 = *(const s8v*)(pb + 8);
        }
        #pragma unroll
        for (int kk = 0; kk < 2; ++kk) {
            int aoff = (w * 16 + r) * 72 + kk * 32 + quad * 8;
            s8v af = *(const s8v*)&As[aoff];
            #pragma unroll
            for (int t = 0; t < 4; ++t) {
                int boff = (t * 16 + r) * 72 + kk * 32 + quad * 8;
                s8v bf = *(const s8v*)&Bs[boff];
                acc[t] = __builtin_amdgcn_mfma_f32_16x16x32_bf16(af, bf, acc[t], 0, 0, 0);
            }
        }
    }
    #pragma unroll
    for (int t = 0; t < 4; ++t) {
        int colg = colBase + t * 16 + r;
        size_t obase = (size_t)(colg >> 10) * (256 * NKP) + (size_t)(colg & 1023);
        #pragma unroll
        for (int reg = 0; reg < 4; ++reg) {
            int row = rowBase + w * 16 + quad * 4 + reg;
            out[obase + (size_t)row * NKP] = acc[t][reg] + biasf[row];
        }
    }
}

// ================= launch =================
extern "C" void kernel_launch(void* const* d_in, const int* in_sizes, int n_in,
                              void* d_out, int out_size, void* d_ws, size_t ws_size,
                              hipStream_t stream) {
    const float* scores  = (const float*)d_in[0];
    const float* d1      = (const float*)d_in[1];
    const float* d2      = (const float*)d_in[2];
    const float* cDa     = (const float*)d_in[3];
    const float* d4      = (const float*)d_in[4];
    const float* lin0_w  = (const float*)d_in[5];
    const float* lin0_b  = (const float*)d_in[6];
    const float* lin1_w  = (const float*)d_in[7];
    const float* lin1_b  = (const float*)d_in[8];
    const float* lin2_w  = (const float*)d_in[9];
    const float* lin2_b  = (const float*)d_in[10];
    const float* merge_w = (const float*)d_in[11];
    const float* merge_b = (const float*)d_in[12];
    float* out = (float*)d_out;

    char* ws = (char*)d_ws;
    float* MASK = (float*)ws;                                          // BHW floats
    short* Xbuf = (short*)ws;                                          // aliases (used after NMS); 5.77 MB
    unsigned long long* cand  = (unsigned long long*)(ws + 14745600);  // 524,288 B
    int* cnt                  = (int*)(ws + 15269888);                 // 1,024 B (padded)
    int* fidx                 = (int*)(ws + 15401984);                 // 16,384 B
    short* Mw                 = (short*)(ws + 15418368);               // 360,448 B (bf16)
    float* biasf              = (float*)(ws + 16139264);               // 1,024 B
    int* perm                 = (int*)(ws + 16140288);                 // 16,384 B

    dim3 tgrid(W / 32, H / 32, B);   // (20,15,4)

    fuse_all<<<705, 256, 0, stream>>>(merge_w, merge_b, lin0_w, lin0_b, lin1_w, lin1_b,
                                      lin2_w, lin2_b, Mw, biasf, cnt);
    nms1<<<tgrid, 256, 0, stream>>>(scores, MASK);
    nms2_compact<<<tgrid, 256, 0, stream>>>(scores, MASK, cand, cnt);
    topk<<<B, 1024, 0, stream>>>(cand, cnt, out, fidx, perm);
    sample_all<<<(B * NKP) / KPB, KTOT, 0, stream>>>(d1, d2, cDa, d4, fidx, perm, Xbuf);
    gemm_mfma<<<dim3(NCOL / 64, 256 / 64), 256, 0, stream>>>(Mw, Xbuf, biasf, out + B * NKP * 3);
}